// Round 6
// baseline (55.202 us; speedup 1.0000x reference)
//
#include <hip/hip_runtime.h>
#include <stdint.h>

typedef unsigned long long u64;
typedef float f32x4 __attribute__((ext_vector_type(4)));

// SC polar decode, N=256, frozen = [0,128). Collapses to:
//   x_j = (in[b,j] + in[b,j+128] >= 0),  j in [0,128)
//   out[b,:] = T(x),  T = F^{(x)7} over GF(2) (self-inverse polar transform).
//
// DIAGNOSTIC ROUND 2: 12 passes. Pass 0 writes d_out (the real result);
// passes 1..11 write identical data to d_ws scratch. Pushes this dispatch to
// ~52 us so it finally ranks above the harness's 40 us fillBuffer dispatches
// in the rocprof top-5, exposing FETCH_SIZE/WRITE_SIZE/VALUBusy for OUR
// kernel. Decisive readout: per-replay overhead O = bench_dur - rocprof_dur.

__device__ __forceinline__ void butterfly128(u64& w0, u64& w1) {
    w0 ^= w1;                                    // top index bit (word select)
    w0 ^= w0 >> 32;                              w1 ^= w1 >> 32;
    w0 ^= (w0 >> 16) & 0x0000FFFF0000FFFFull;    w1 ^= (w1 >> 16) & 0x0000FFFF0000FFFFull;
    w0 ^= (w0 >> 8)  & 0x00FF00FF00FF00FFull;    w1 ^= (w1 >> 8)  & 0x00FF00FF00FF00FFull;
    w0 ^= (w0 >> 4)  & 0x0F0F0F0F0F0F0F0Full;    w1 ^= (w1 >> 4)  & 0x0F0F0F0F0F0F0F0Full;
    w0 ^= (w0 >> 2)  & 0x3333333333333333ull;    w1 ^= (w1 >> 2)  & 0x3333333333333333ull;
    w0 ^= (w0 >> 1)  & 0x5555555555555555ull;    w1 ^= (w1 >> 1)  & 0x5555555555555555ull;
}

__global__ __launch_bounds__(256) void sc_dec_kernel(const float* __restrict__ in,
                                                     float* __restrict__ out,
                                                     float* __restrict__ ws,
                                                     int rows) {
    const int lane = threadIdx.x & 63;
    const int h = lane >> 5;          // which row of the pair this lane serves
    const int m = lane & 31;
    const int wave = blockIdx.x * (blockDim.x >> 6) + (threadIdx.x >> 6);
    const int r = wave * 4;           // 4 rows per wave (2 pairs)
    if (r >= rows) return;

    #pragma unroll 1
    for (int pass = 0; pass < 12; ++pass) {
        float* tgt = (pass == 0) ? out : ws;   // real output only on pass 0

        if (r + 4 <= rows) {
            const f32x4* b0 = reinterpret_cast<const f32x4*>(in + (size_t)r * 256);
            const f32x4* b1 = reinterpret_cast<const f32x4*>(in + (size_t)(r + 2) * 256);
            const int oA = (h << 6) + m;  // row (pr+h) first half  (f32x4 units)
            const int oB = oA + 32;       // row (pr+h) second half
            f32x4 A0 = b0[oA];
            f32x4 B0 = b0[oB];
            f32x4 A1 = b1[oA];
            f32x4 B1 = b1[oB];

            // pair 0: rows r, r+1
            u64 M0 = __ballot(A0.x + B0.x >= 0.0f);
            u64 M1 = __ballot(A0.y + B0.y >= 0.0f);
            u64 M2 = __ballot(A0.z + B0.z >= 0.0f);
            u64 M3 = __ballot(A0.w + B0.w >= 0.0f);
            u64 a0 = (M0 & 0xFFFFFFFFull) | (M1 << 32);
            u64 a1 = (M2 & 0xFFFFFFFFull) | (M3 << 32);
            u64 c0 = (M0 >> 32) | (M1 & 0xFFFFFFFF00000000ull);
            u64 c1 = (M2 >> 32) | (M3 & 0xFFFFFFFF00000000ull);
            butterfly128(a0, a1);
            butterfly128(c0, c1);
            u64 w0 = h ? c0 : a0, w1 = h ? c1 : a1;
            f32x4 o;
            o.x = (float)((w0 >> m) & 1ull);
            o.y = (float)((w0 >> (m + 32)) & 1ull);
            o.z = (float)((w1 >> m) & 1ull);
            o.w = (float)((w1 >> (m + 32)) & 1ull);
            reinterpret_cast<f32x4*>(tgt + (size_t)r * 128)[(h << 5) + m] = o;

            // pair 1: rows r+2, r+3
            M0 = __ballot(A1.x + B1.x >= 0.0f);
            M1 = __ballot(A1.y + B1.y >= 0.0f);
            M2 = __ballot(A1.z + B1.z >= 0.0f);
            M3 = __ballot(A1.w + B1.w >= 0.0f);
            a0 = (M0 & 0xFFFFFFFFull) | (M1 << 32);
            a1 = (M2 & 0xFFFFFFFFull) | (M3 << 32);
            c0 = (M0 >> 32) | (M1 & 0xFFFFFFFF00000000ull);
            c1 = (M2 >> 32) | (M3 & 0xFFFFFFFF00000000ull);
            butterfly128(a0, a1);
            butterfly128(c0, c1);
            w0 = h ? c0 : a0; w1 = h ? c1 : a1;
            o.x = (float)((w0 >> m) & 1ull);
            o.y = (float)((w0 >> (m + 32)) & 1ull);
            o.z = (float)((w1 >> m) & 1ull);
            o.w = (float)((w1 >> (m + 32)) & 1ull);
            reinterpret_cast<f32x4*>(tgt + (size_t)(r + 2) * 128)[(h << 5) + m] = o;
        } else {
            // tail fallback (rows % 4 != 0): per-row float2 scheme
            for (int row = r; row < rows; ++row) {
                const float2* rin = reinterpret_cast<const float2*>(in + (size_t)row * 256);
                float2 a = rin[lane];
                float2 c = rin[64 + lane];
                u64 w0 = __ballot(a.x + c.x >= 0.0f);
                u64 w1 = __ballot(a.y + c.y >= 0.0f);
                butterfly128(w0, w1);
                float2 o;
                o.x = (float)((w0 >> lane) & 1ull);
                o.y = (float)((w1 >> lane) & 1ull);
                reinterpret_cast<float2*>(tgt + (size_t)row * 128)[lane] = o;
            }
        }
        asm volatile("" ::: "memory");   // keep every pass live (no DSE)
    }
}

extern "C" void kernel_launch(void* const* d_in, const int* in_sizes, int n_in,
                              void* d_out, int out_size, void* d_ws, size_t ws_size,
                              hipStream_t stream) {
    const float* in = (const float*)d_in[0];
    float* out = (float*)d_out;
    float* ws = (float*)d_ws;                      // >= 16 MB scratch (poisoned, we own it)
    const int rows = in_sizes[0] / 256;            // 32768

    const int waves = (rows + 3) / 4;              // 4 rows per wave
    const int blocks = (waves + 3) / 4;            // 4 waves per 256-thread block
    sc_dec_kernel<<<blocks, 256, 0, stream>>>(in, out, ws, rows);
}

// Round 7
// 12.351 us; speedup vs baseline: 4.4694x; 4.4694x over previous
//
#include <hip/hip_runtime.h>
#include <stdint.h>

typedef unsigned long long u64;
typedef float f32x4 __attribute__((ext_vector_type(4)));

// SC polar decode, N=256, frozen = [0,128). Collapses algebraically to:
//   x_j = (in[b,j] + in[b,j+128] >= 0),  j in [0,128)
//   out[b,:] = T(x),  T = F^{(x)7} over GF(2) (self-inverse polar transform).
// T is equivariant under any permutation of the 7 index BITS, so the
// word-butterfly runs directly in the packed bit-domain the ballots produce.
//
// Final form (R3 structure, fastest measured: 12.35 us):
//   dur = ~8.4 us fixed per-replay harness overhead (invariant across 5
//   structural variants, R1-R6 pass-count fit) + ~3.9 us kernel moving the
//   algorithmically minimal 48 MB at ~12.3 TB/s (MALL-resident BW, ~2x HBM).

__device__ __forceinline__ void butterfly128(u64& w0, u64& w1) {
    w0 ^= w1;                                    // top index bit (word select)
    w0 ^= w0 >> 32;                              w1 ^= w1 >> 32;
    w0 ^= (w0 >> 16) & 0x0000FFFF0000FFFFull;    w1 ^= (w1 >> 16) & 0x0000FFFF0000FFFFull;
    w0 ^= (w0 >> 8)  & 0x00FF00FF00FF00FFull;    w1 ^= (w1 >> 8)  & 0x00FF00FF00FF00FFull;
    w0 ^= (w0 >> 4)  & 0x0F0F0F0F0F0F0F0Full;    w1 ^= (w1 >> 4)  & 0x0F0F0F0F0F0F0F0Full;
    w0 ^= (w0 >> 2)  & 0x3333333333333333ull;    w1 ^= (w1 >> 2)  & 0x3333333333333333ull;
    w0 ^= (w0 >> 1)  & 0x5555555555555555ull;    w1 ^= (w1 >> 1)  & 0x5555555555555555ull;
}

__global__ __launch_bounds__(256) void sc_dec_kernel(const float* __restrict__ in,
                                                     float* __restrict__ out,
                                                     int rows) {
    const int lane = threadIdx.x & 63;
    const int h = lane >> 5;          // which row of the pair this lane serves
    const int m = lane & 31;
    const int wave = blockIdx.x * (blockDim.x >> 6) + (threadIdx.x >> 6);
    const int r = wave * 4;           // 4 rows per wave (2 pairs)
    if (r >= rows) return;

    if (r + 4 <= rows) {
        const f32x4* b0 = reinterpret_cast<const f32x4*>(in + (size_t)r * 256);
        const f32x4* b1 = reinterpret_cast<const f32x4*>(in + (size_t)(r + 2) * 256);
        const int oA = (h << 6) + m;  // row (pr+h) first half  (f32x4 units)
        const int oB = oA + 32;       // row (pr+h) second half
        // hoist all 4 loads (4 KiB/wave in flight)
        f32x4 A0 = __builtin_nontemporal_load(&b0[oA]);
        f32x4 B0 = __builtin_nontemporal_load(&b0[oB]);
        f32x4 A1 = __builtin_nontemporal_load(&b1[oA]);
        f32x4 B1 = __builtin_nontemporal_load(&b1[oB]);

        // pair 0: rows r, r+1 (lanes 0-31 row r, lanes 32-63 row r+1)
        u64 M0 = __ballot(A0.x + B0.x >= 0.0f);
        u64 M1 = __ballot(A0.y + B0.y >= 0.0f);
        u64 M2 = __ballot(A0.z + B0.z >= 0.0f);
        u64 M3 = __ballot(A0.w + B0.w >= 0.0f);
        u64 a0 = (M0 & 0xFFFFFFFFull) | (M1 << 32);
        u64 a1 = (M2 & 0xFFFFFFFFull) | (M3 << 32);
        u64 c0 = (M0 >> 32) | (M1 & 0xFFFFFFFF00000000ull);
        u64 c1 = (M2 >> 32) | (M3 & 0xFFFFFFFF00000000ull);
        butterfly128(a0, a1);
        butterfly128(c0, c1);
        u64 w0 = h ? c0 : a0, w1 = h ? c1 : a1;
        f32x4 o;
        o.x = (float)((w0 >> m) & 1ull);
        o.y = (float)((w0 >> (m + 32)) & 1ull);
        o.z = (float)((w1 >> m) & 1ull);
        o.w = (float)((w1 >> (m + 32)) & 1ull);
        f32x4* ob0 = reinterpret_cast<f32x4*>(out + (size_t)r * 128);
        __builtin_nontemporal_store(o, &ob0[(h << 5) + m]);

        // pair 1: rows r+2, r+3
        M0 = __ballot(A1.x + B1.x >= 0.0f);
        M1 = __ballot(A1.y + B1.y >= 0.0f);
        M2 = __ballot(A1.z + B1.z >= 0.0f);
        M3 = __ballot(A1.w + B1.w >= 0.0f);
        a0 = (M0 & 0xFFFFFFFFull) | (M1 << 32);
        a1 = (M2 & 0xFFFFFFFFull) | (M3 << 32);
        c0 = (M0 >> 32) | (M1 & 0xFFFFFFFF00000000ull);
        c1 = (M2 >> 32) | (M3 & 0xFFFFFFFF00000000ull);
        butterfly128(a0, a1);
        butterfly128(c0, c1);
        w0 = h ? c0 : a0; w1 = h ? c1 : a1;
        o.x = (float)((w0 >> m) & 1ull);
        o.y = (float)((w0 >> (m + 32)) & 1ull);
        o.z = (float)((w1 >> m) & 1ull);
        o.w = (float)((w1 >> (m + 32)) & 1ull);
        f32x4* ob1 = reinterpret_cast<f32x4*>(out + (size_t)(r + 2) * 128);
        __builtin_nontemporal_store(o, &ob1[(h << 5) + m]);
    } else {
        // tail fallback (rows % 4 != 0): per-row float2 scheme
        for (int row = r; row < rows; ++row) {
            const float2* rin = reinterpret_cast<const float2*>(in + (size_t)row * 256);
            float2 a = rin[lane];
            float2 c = rin[64 + lane];
            u64 w0 = __ballot(a.x + c.x >= 0.0f);
            u64 w1 = __ballot(a.y + c.y >= 0.0f);
            butterfly128(w0, w1);
            float2 o;
            o.x = (float)((w0 >> lane) & 1ull);
            o.y = (float)((w1 >> lane) & 1ull);
            reinterpret_cast<float2*>(out + (size_t)row * 128)[lane] = o;
        }
    }
}

extern "C" void kernel_launch(void* const* d_in, const int* in_sizes, int n_in,
                              void* d_out, int out_size, void* d_ws, size_t ws_size,
                              hipStream_t stream) {
    const float* in = (const float*)d_in[0];
    float* out = (float*)d_out;
    const int rows = in_sizes[0] / 256;            // 32768

    const int waves = (rows + 3) / 4;              // 4 rows per wave
    const int blocks = (waves + 3) / 4;            // 4 waves per 256-thread block
    sc_dec_kernel<<<blocks, 256, 0, stream>>>(in, out, rows);
}